// Round 7
// baseline (358.571 us; speedup 1.0000x reference)
//
#include <hip/hip_runtime.h>

// out[b,s] = capped_relu( sum_c x[b,c,s] * W[c,s] + bias[s] )
// B=64, C=256, S=4096, all float32. Memory-bound (0.5 FLOP/B).
// x = 256 MiB streamed; W = 4 MiB (L2/L3-resident).
//
// Channel-split: C-reduction across 4 thread-groups per block
// (LDS combine) to raise occupancy from 1 wave/SIMD to 4 waves/SIMD.

#define BATCH    64
#define CHANNELS 256
#define SIZE     4096

#define CG   4                 // channel-split groups per block
#define TS   512               // s-floats per block tile
#define TPG  (TS / 4)          // threads per group (float4 each) = 128
#define TPB  (CG * TPG)        // 512 threads/block
#define CPG  (CHANNELS / CG)   // 64 channels per group
#define NTILE (SIZE / TS)      // 8 s-tiles per batch row

__device__ __forceinline__ float capped_relu(float v) {
    return (v > 0.0f && v <= 1.0f) ? v : 0.0f;
}

__global__ __launch_bounds__(TPB) void CWG_30794915512765_kernel(
    const float* __restrict__ x,
    const float* __restrict__ w,
    const float* __restrict__ bias,
    float* __restrict__ out)
{
    __shared__ float4 part[CG - 1][TPG];   // 3 * 128 * 16 B = 6 KB

    const int tid = threadIdx.x;
    const int g   = tid >> 7;          // c-group 0..3
    const int t   = tid & (TPG - 1);   // s-thread within group
    const int bid = blockIdx.x;
    const int b     = bid >> 3;        // / NTILE
    const int stile = bid & (NTILE - 1);
    const int s     = stile * TS + (t << 2);

    const float* xp = x + (size_t)b * CHANNELS * SIZE + (size_t)g * CPG * SIZE + s;
    const float* wp = w + (size_t)g * CPG * SIZE + s;

    float4 acc = make_float4(0.0f, 0.0f, 0.0f, 0.0f);

#pragma unroll 8
    for (int c = 0; c < CPG; ++c) {
        const float4 xv = *reinterpret_cast<const float4*>(xp + (size_t)c * SIZE);
        const float4 wv = *reinterpret_cast<const float4*>(wp + (size_t)c * SIZE);
        acc.x += xv.x * wv.x;
        acc.y += xv.y * wv.y;
        acc.z += xv.z * wv.z;
        acc.w += xv.w * wv.w;
    }

    if (g != 0) part[g - 1][t] = acc;
    __syncthreads();

    if (g == 0) {
#pragma unroll
        for (int k = 0; k < CG - 1; ++k) {
            const float4 p = part[k][t];
            acc.x += p.x; acc.y += p.y; acc.z += p.z; acc.w += p.w;
        }
        const float4 bv = *reinterpret_cast<const float4*>(bias + s);
        float4 o;
        o.x = capped_relu(acc.x + bv.x);
        o.y = capped_relu(acc.y + bv.y);
        o.z = capped_relu(acc.z + bv.z);
        o.w = capped_relu(acc.w + bv.w);
        *reinterpret_cast<float4*>(out + (size_t)b * SIZE + s) = o;
    }
}

extern "C" void kernel_launch(void* const* d_in, const int* in_sizes, int n_in,
                              void* d_out, int out_size, void* d_ws, size_t ws_size,
                              hipStream_t stream) {
    const float* x    = (const float*)d_in[0];
    const float* w    = (const float*)d_in[1];
    const float* bias = (const float*)d_in[2];
    float* out        = (float*)d_out;

    const int blocks = BATCH * NTILE;  // 64 * 8 = 512
    CWG_30794915512765_kernel<<<blocks, TPB, 0, stream>>>(x, w, bias, out);
}